// Round 2
// 230.680 us; speedup vs baseline: 1.1542x; 1.1542x over previous
//
#include <hip/hip_runtime.h>
#include <math.h>

// Problem constants: N=500000, NFEAT=64, K=8, HK=64
constexpr int NS    = 500000;
constexpr int NF    = 64;
constexpr int KG    = 8;
constexpr int HKC   = 64;
constexpr int NCELL = KG * HKC;            // 512 histogram cells
constexpr int RPW   = 32;                  // rows per wave (NS % 32 == 0)
constexpr int TPB   = 1024;                // 16 waves per block
constexpr int NBLK  = 256;                 // 1 block per CU (132 KB LDS)
constexpr int NTILE = NS / RPW;            // 15625 row-tiles (exact)
constexpr int NWAVES = NBLK * (TPB / 64);  // 4096 waves, grid-stride over tiles
constexpr int SLICE = HKC * NF;            // 4096 halves = 8 KB per (g, hi|lo)

typedef __attribute__((ext_vector_type(8))) _Float16 half8;
typedef __attribute__((ext_vector_type(4))) float f32x4;

// xor-16 within 32-lane halves: ds_swizzle BitMode offset 0x401F
__device__ __forceinline__ float swz16_f(float v) {
    return __int_as_float(__builtin_amdgcn_ds_swizzle(__float_as_int(v), 0x401F));
}
__device__ __forceinline__ int swz16_i(int v) {
    return __builtin_amdgcn_ds_swizzle(v, 0x401F);
}

// Kernel 1: w = exp(z) split to fp16 hi/lo; zero A (main kernel atomically
// accumulates the histogram straight into A now — no partial buffer).
__global__ void prep_kernel(const float* __restrict__ z,
                            _Float16* __restrict__ w_hi,
                            _Float16* __restrict__ w_lo,
                            float* __restrict__ A) {
    int i = blockIdx.x * blockDim.x + threadIdx.x;
    if (i < KG * HKC * NF) {
        float w = expf(z[i]);
        _Float16 h = (_Float16)w;           // RNE
        w_hi[i] = h;
        w_lo[i] = (_Float16)(w - (float)h); // residual: ~2^-22 total pair error
    }
    if (i < NCELL) A[i] = 0.0f;
}

// Main kernel, persistent-W redesign (R8/R9): 256 blocks x 1024 threads,
// 1 block per CU. ALL 8 groups' w slices (hi+lo, 128 KB, XOR-swizzled 16B
// chunks) + t + hist are staged into LDS ONCE, then each wave grid-strides
// over 32-row tiles with ZERO barriers and ZERO staging in the loop
// (R7 stall source: 16 syncthreads/block each draining a 16 KB L2 restage
// of block-invariant data -> both pipes only ~34% busy). Inner loop is
// byte-identical to the verified R7 kernel -> bit-identical y and A.
// LDS: 131072 + 2048 + 2048 = 135168 B < 163840 B gfx950 per-WG limit.
// __launch_bounds__(1024,4): 128-reg budget; R7 measured 56 VGPR + 32 AGPR.
__global__ __launch_bounds__(TPB, 4) void monn_mfma_kernel(
    const float* __restrict__ x,
    const _Float16* __restrict__ w_hi,
    const _Float16* __restrict__ w_lo,
    const float* __restrict__ t,
    float* __restrict__ y,
    float* __restrict__ A) {

    __shared__ __align__(16) char smem[2 * KG * 8192];   // hi @0, lo @65536
    __shared__ __align__(16) float t_lds[KG * HKC];      // 2 KB
    __shared__ unsigned lhist[NCELL];

    const int tid = threadIdx.x;

    // --- one-time staging: 128 KB of w (coalesced, XOR-swizzled), t, hist ---
    {
        const float4* sh = reinterpret_cast<const float4*>(w_hi);
        const float4* sl = reinterpret_cast<const float4*>(w_lo);
#pragma unroll
        for (int i = 0; i < 4; ++i) {
            const int ci  = i * 1024 + tid;         // 16B chunk id, 0..4095
            const int row = (ci >> 3) & 63;         // w-col within group
            const int ch  = ci & 7;                 // 16B chunk within row
            const int addr = (ci >> 9) * 8192 + row * 128 + ((ch ^ (row & 7)) << 4);
            *reinterpret_cast<float4*>(smem + addr)         = sh[ci];
            *reinterpret_cast<float4*>(smem + 65536 + addr) = sl[ci];
        }
        if (tid < 128)
            reinterpret_cast<float4*>(t_lds)[tid] =
                reinterpret_cast<const float4*>(t)[tid];
        if (tid < NCELL) lhist[tid] = 0u;
    }
    __syncthreads();   // the ONLY barrier before the final flush

    const int lane = tid & 63;
    const int m  = lane & 15;
    const int q  = lane >> 4;
    const int q4 = q * 4;
    const int a32 = ((lane ^ 32) << 2);   // ds_bpermute byte-addr for xor-32
    const int x7  = m & 7;
    const int rb0 = m * 128 + (((0 + q) ^ x7) << 4);
    const int rb1 = m * 128 + (((4 + q) ^ x7) << 4);
    const int gwave = blockIdx.x * (TPB / 64) + (tid >> 6);

#pragma unroll 1
    for (int tile = gwave; tile < NTILE; tile += NWAVES) {
        const long base = (long)tile * RPW;

        // --- Load 32 x rows, split to fp16 hi/lo (B-operand layout) ---
        half8 Xh[2][2], Xl[2][2];
#pragma unroll
        for (int rt = 0; rt < 2; ++rt) {
            const float* xp = x + (base + rt * 16 + m) * NF;
#pragma unroll
            for (int s = 0; s < 2; ++s) {
                const int k0 = s * 32 + q * 8;
                const float4 v0 = *reinterpret_cast<const float4*>(xp + k0);
                const float4 v1 = *reinterpret_cast<const float4*>(xp + k0 + 4);
                const float f[8] = {v0.x, v0.y, v0.z, v0.w, v1.x, v1.y, v1.z, v1.w};
#pragma unroll
                for (int j = 0; j < 8; ++j) {
                    _Float16 h = (_Float16)f[j];
                    Xh[rt][s][j] = h;
                    Xl[rt][s][j] = (_Float16)(f[j] - (float)h);
                }
            }
        }

        float ymin[2] = {INFINITY, INFINITY};
        int   code[2] = {0, 0};

#pragma unroll 1
        for (int g = 0; g < KG; ++g) {
            // bias folded into acc init: lane's w-cols are c*16 + q4 + j
            f32x4 acc[4][2];   // [c (w tile)][rt (x tile)]
#pragma unroll
            for (int c = 0; c < 4; ++c) {
                const float4 tv = *reinterpret_cast<const float4*>(
                    t_lds + g * HKC + c * 16 + q4);
                acc[c][0] = (f32x4){tv.x, tv.y, tv.z, tv.w};
                acc[c][1] = acc[c][0];
            }

#pragma unroll
            for (int s = 0; s < 2; ++s) {
                const int rb = (s ? rb1 : rb0) + g * 8192;
                half8 Wh[4], Wl[4];
#pragma unroll
                for (int c = 0; c < 4; ++c) {   // ds_read_b128, imm offsets
                    Wh[c] = *reinterpret_cast<const half8*>(smem + rb + c * 2048);
                    Wl[c] = *reinterpret_cast<const half8*>(smem + 65536 + rb + c * 2048);
                }
                // 3 independent passes (hh, lh, hl): same order as R7 ->
                // bit-identical accumulation
#pragma unroll
                for (int c = 0; c < 4; ++c)
#pragma unroll
                    for (int rt = 0; rt < 2; ++rt)
                        acc[c][rt] = __builtin_amdgcn_mfma_f32_16x16x32_f16(Wh[c], Xh[rt][s], acc[c][rt], 0, 0, 0);
#pragma unroll
                for (int c = 0; c < 4; ++c)
#pragma unroll
                    for (int rt = 0; rt < 2; ++rt)
                        acc[c][rt] = __builtin_amdgcn_mfma_f32_16x16x32_f16(Wl[c], Xh[rt][s], acc[c][rt], 0, 0, 0);
#pragma unroll
                for (int c = 0; c < 4; ++c)
#pragma unroll
                    for (int rt = 0; rt < 2; ++rt)
                        acc[c][rt] = __builtin_amdgcn_mfma_f32_16x16x32_f16(Wh[c], Xl[rt][s], acc[c][rt], 0, 0, 0);
            }

            // --- epilogue: per x-row argmax over this group's 64 w-cols ---
#pragma unroll
            for (int rt = 0; rt < 2; ++rt) {
                float t01 = fmaxf(acc[0][rt][0], acc[0][rt][1]);
                float t23 = fmaxf(acc[0][rt][2], acc[0][rt][3]);
                float t45 = fmaxf(acc[1][rt][0], acc[1][rt][1]);
                float t67 = fmaxf(acc[1][rt][2], acc[1][rt][3]);
                float t89 = fmaxf(acc[2][rt][0], acc[2][rt][1]);
                float tab = fmaxf(acc[2][rt][2], acc[2][rt][3]);
                float tcd = fmaxf(acc[3][rt][0], acc[3][rt][1]);
                float tef = fmaxf(acc[3][rt][2], acc[3][rt][3]);
                float v = fmaxf(fmaxf(fmaxf(t01, t23), fmaxf(t45, t67)),
                                fmaxf(fmaxf(t89, tab), fmaxf(tcd, tef)));
                // equality scan, descending w-col: last write = smallest ->
                // jnp.argmax first-occurrence semantics (w-col = c*16 + q4 + j)
                int h = 0;
#pragma unroll
                for (int c = 3; c >= 0; --c)
#pragma unroll
                    for (int j = 3; j >= 0; --j)
                        h = (acc[c][rt][j] == v) ? (c * 16 + j) : h;
                h |= q4;
                // cross-q combine (4 lanes, stride 16): xor16 + xor32
                {
                    float v2 = swz16_f(v);
                    int   h2 = swz16_i(h);
                    bool take = (v2 > v) || (v2 == v && h2 < h);
                    v = take ? v2 : v;  h = take ? h2 : h;
                    float v3 = __int_as_float(__builtin_amdgcn_ds_bpermute(a32, __float_as_int(v)));
                    int   h3 = __builtin_amdgcn_ds_bpermute(a32, h);
                    take = (v3 > v) || (v3 == v && h3 < h);
                    v = take ? v3 : v;  h = take ? h3 : h;
                }
                // running min over groups: strict < keeps first (lowest g)
                const bool better = v < ymin[rt];
                ymin[rt] = fminf(ymin[rt], v);
                code[rt] = better ? ((g << 6) | h) : code[rt];
            }
        }

        // q==0 lanes write y and bump the block histogram (LDS, banked)
        if (q == 0) {
#pragma unroll
            for (int rt = 0; rt < 2; ++rt) {
                y[base + rt * 16 + m] = ymin[rt];
                atomicAdd(&lhist[code[rt]], 1u);
            }
        }
    }

    __syncthreads();
    // zero-skip flush straight into A: 256 blocks x <=512 cells ->
    // <=256 conflicting atomics per address, negligible
    for (int i = tid; i < NCELL; i += TPB) {
        const unsigned c = lhist[i];
        if (c) atomicAdd(&A[i], (float)c);
    }
}

extern "C" void kernel_launch(void* const* d_in, const int* in_sizes, int n_in,
                              void* d_out, int out_size, void* d_ws, size_t ws_size,
                              hipStream_t stream) {
    const float* x = (const float*)d_in[0];  // [NS, NF]
    const float* z = (const float*)d_in[1];  // [KG, HKC, NF]
    const float* t = (const float*)d_in[2];  // [KG, HKC]

    float* y = (float*)d_out;        // [NS]
    float* A = (float*)d_out + NS;   // [NCELL]

    _Float16* w_hi = (_Float16*)d_ws;                          // 64 KB
    _Float16* w_lo = w_hi + (size_t)KG * HKC * NF;             // 64 KB

    prep_kernel<<<128, 256, 0, stream>>>(z, w_hi, w_lo, A);
    monn_mfma_kernel<<<NBLK, TPB, 0, stream>>>(x, w_hi, w_lo, t, y, A);
}